// Round 4
// baseline (437.132 us; speedup 1.0000x reference)
//
#include <hip/hip_runtime.h>

// SplitLinear: out[b, o*C + c] = sum_s x[b, s*C + c] * w[o, s, c] + bias[o*C + c]
// x: [64, 1e6] fp32, w: [4, 400, 2500] fp32, bias: [10000], out: [64, 10000]
//
// Memory-streaming problem. dur_us includes ~250 us fixed harness reset
// (256 MB input restore + 1 GB ws poison at ~6.6 TB/s); controllable part:
// R2 (BT=4, w streamed) ~128 us, R3 (BT=1) ~151 us (w traffic x4 -> L3-bound).
// R4: w staged in LDS once per block => steady-state loop has ZERO global
// w-loads; x is the only global stream (read exactly once, 256 MB).
// Block = 256 thr = 4 waves sharing one 64 KB w-slice (4o x 16s x 256c fp32);
// each wave: 8 b rows, 2 passes of 4-row accumulators; grid (10, 2, 25).

constexpr int IN_F   = 1000000;
constexpr int S_DIM  = 400;
constexpr int C_DIM  = 2500;
constexpr int O_SETS = 4;
constexpr int B_SZ   = 64;
constexpr int OC     = O_SETS * C_DIM;    // 10000
constexpr int OUT_N  = B_SZ * OC;         // 640000

constexpr int NQ     = C_DIM / 4;         // 625 float4 quads along c
constexpr int QW     = (NQ + 63) / 64;    // 10 c-blocks of 64 quads
constexpr int NSPLIT = 25;                // s segments
constexpr int SSEG   = S_DIM / NSPLIT;    // 16 s-steps per segment
constexpr int BG     = 2;                 // b groups (32 rows each)
constexpr int BPW    = 8;                 // b rows per wave
constexpr int BT_IN  = 4;                 // acc rows per pass (2 passes)

constexpr size_t WS_NEED = (size_t)NSPLIT * OUT_N * sizeof(float);  // 64 MB

__device__ __forceinline__ void fma4(float4& a, const float4& p, const float4& q) {
    a.x = fmaf(p.x, q.x, a.x);
    a.y = fmaf(p.y, q.y, a.y);
    a.z = fmaf(p.z, q.z, a.z);
    a.w = fmaf(p.w, q.w, a.w);
}

// ---------------- Main path ----------------

// grid (QW, BG, NSPLIT), block 256. LDS: w[o][s][quad] float4, 64 KB.
__global__ __launch_bounds__(256) void sl_part(const float* __restrict__ x,
                                               const float* __restrict__ w,
                                               float* __restrict__ ws) {
    __shared__ float4 wlds[O_SETS][SSEG][64];   // 64 KB

    const int tid = threadIdx.x;
    const int q0  = blockIdx.x * 64;
    const int z   = blockIdx.z;
    const int s0  = z * SSEG;

    // Cooperative w staging: 4096 float4 / 256 thr = 16 each. Row r=(o,s) has
    // 64 float4; f = tid + k*256 -> r = f/64 = o*16+s, col = f%64.
#pragma unroll
    for (int k = 0; k < 16; ++k) {
        const int f   = tid + k * 256;
        const int r   = f >> 6;
        const int col = f & 63;
        const int o   = r >> 4;          // SSEG == 16
        const int s   = r & 15;
        int gq = q0 + col; if (gq >= NQ) gq = NQ - 1;   // clamp (dup, unused)
        wlds[o][s][col] =
            *(const float4*)(w + (size_t)o * (S_DIM * C_DIM)
                               + (size_t)(s0 + s) * C_DIM + (size_t)gq * 4);
    }
    __syncthreads();

    const int lane = tid & 63;
    const int wv   = tid >> 6;
    const int q    = q0 + lane;
    const bool act = (q < NQ);
    const int qc   = act ? q : 0;        // clamped: junk loads stay in-bounds

#pragma unroll
    for (int pass = 0; pass < 2; ++pass) {
        const int b0 = blockIdx.y * (BPW * 4) + wv * BPW + pass * BT_IN;

        const float4* xp[BT_IN];
#pragma unroll
        for (int i = 0; i < BT_IN; ++i)
            xp[i] = (const float4*)(x + (size_t)(b0 + i) * IN_F
                                      + (size_t)s0 * C_DIM) + qc;

        float4 acc[BT_IN][O_SETS];
#pragma unroll
        for (int i = 0; i < BT_IN; ++i)
#pragma unroll
            for (int o = 0; o < O_SETS; ++o)
                acc[i][o] = make_float4(0.f, 0.f, 0.f, 0.f);

        // x ping-pong (only global loads in the loop)
        float4 xb[2][BT_IN];
#pragma unroll
        for (int i = 0; i < BT_IN; ++i) { xb[0][i] = *xp[i]; xp[i] += C_DIM / 4; }

#pragma unroll
        for (int s = 0; s < SSEG; ++s) {
            const int cur = s & 1, nxt = cur ^ 1;
            if (s + 1 < SSEG) {
#pragma unroll
                for (int i = 0; i < BT_IN; ++i) { xb[nxt][i] = *xp[i]; xp[i] += C_DIM / 4; }
            }
            float4 wv4[O_SETS];
#pragma unroll
            for (int o = 0; o < O_SETS; ++o) wv4[o] = wlds[o][s][lane];
#pragma unroll
            for (int i = 0; i < BT_IN; ++i)
#pragma unroll
                for (int o = 0; o < O_SETS; ++o)
                    fma4(acc[i][o], xb[cur][i], wv4[o]);
        }

        if (act) {
            float* base = ws + (size_t)z * OUT_N;
#pragma unroll
            for (int i = 0; i < BT_IN; ++i) {
                float* orow = base + (size_t)(b0 + i) * OC;
#pragma unroll
                for (int o = 0; o < O_SETS; ++o)
                    *(float4*)(orow + o * C_DIM + q * 4) = acc[i][o];
            }
        }
    }
}

// out[idx] = bias[idx % OC] + sum_z ws[z][idx]
__global__ __launch_bounds__(256) void sl_reduce(const float* __restrict__ ws,
                                                 const float* __restrict__ bias,
                                                 float* __restrict__ out) {
    const int t = blockIdx.x * 256 + threadIdx.x;
    if (t >= OUT_N / 4) return;
    const int idx = t * 4;
    const int oc  = idx % OC;

    float4 s = *(const float4*)(bias + oc);
#pragma unroll
    for (int z = 0; z < NSPLIT; ++z) {
        float4 v = *(const float4*)(ws + (size_t)z * OUT_N + idx);
        s.x += v.x; s.y += v.y; s.z += v.z; s.w += v.w;
    }
    *(float4*)(out + idx) = s;
}

// ---------------- Fallback (ws too small): atomics ----------------

__global__ __launch_bounds__(256) void sl_init(const float* __restrict__ bias,
                                               float* __restrict__ out) {
    int j = blockIdx.x * 256 + threadIdx.x;
    if (j < OC) out[(size_t)blockIdx.y * OC + j] = bias[j];
}

__global__ __launch_bounds__(64) void sl_atomic(const float* __restrict__ x,
                                                const float* __restrict__ w,
                                                float* __restrict__ out) {
    const int lane = threadIdx.x;
    const int q    = blockIdx.x * 64 + lane;
    if (q >= NQ) return;
    const int b  = blockIdx.y;
    const int s0 = blockIdx.z * SSEG;

    const float4* xp = (const float4*)(x + (size_t)b * IN_F + (size_t)s0 * C_DIM) + q;
    const float4* wp[O_SETS];
#pragma unroll
    for (int o = 0; o < O_SETS; ++o)
        wp[o] = (const float4*)(w + (size_t)o * (S_DIM * C_DIM) + (size_t)s0 * C_DIM) + q;

    float4 acc[O_SETS];
#pragma unroll
    for (int o = 0; o < O_SETS; ++o) acc[o] = make_float4(0.f, 0.f, 0.f, 0.f);

    for (int s = 0; s < SSEG; ++s) {
        float4 xv = *xp; xp += C_DIM / 4;
        float4 wv4[O_SETS];
#pragma unroll
        for (int o = 0; o < O_SETS; ++o) { wv4[o] = *wp[o]; wp[o] += C_DIM / 4; }
#pragma unroll
        for (int o = 0; o < O_SETS; ++o) fma4(acc[o], xv, wv4[o]);
    }

    float* orow = out + (size_t)b * OC;
#pragma unroll
    for (int o = 0; o < O_SETS; ++o) {
        float* dst = orow + o * C_DIM + q * 4;
        atomicAdd(dst + 0, acc[o].x);
        atomicAdd(dst + 1, acc[o].y);
        atomicAdd(dst + 2, acc[o].z);
        atomicAdd(dst + 3, acc[o].w);
    }
}

extern "C" void kernel_launch(void* const* d_in, const int* in_sizes, int n_in,
                              void* d_out, int out_size, void* d_ws, size_t ws_size,
                              hipStream_t stream) {
    const float* x    = (const float*)d_in[0];
    const float* wgt  = (const float*)d_in[1];
    const float* bias = (const float*)d_in[2];
    float* out = (float*)d_out;

    if (ws_size >= WS_NEED) {
        float* ws = (float*)d_ws;
        dim3 g(QW, BG, NSPLIT);
        sl_part<<<g, 256, 0, stream>>>(x, wgt, ws);
        sl_reduce<<<(OUT_N / 4 + 255) / 256, 256, 0, stream>>>(ws, bias, out);
    } else {
        dim3 gInit((OC + 255) / 256, B_SZ);
        sl_init<<<gInit, 256, 0, stream>>>(bias, out);
        dim3 g(QW, B_SZ, NSPLIT);
        sl_atomic<<<g, 64, 0, stream>>>(x, wgt, out);
    }
}

// Round 5
// 399.882 us; speedup vs baseline: 1.0932x; 1.0932x over previous
//
#include <hip/hip_runtime.h>

// SplitLinear: out[b, o*C + c] = sum_s x[b, s*C + c] * w[o, s, c] + bias[o*C + c]
// x: [64, 1e6] fp32, w: [4, 400, 2500] fp32, bias: [10000], out: [64, 10000]
//
// R4 post-mortem: LDS-staged w hit the 256-VGPR cap and SPILLED (WRITE_SIZE
// 114 MB vs 66 expected) -> 195 us. Negative result: removing in-loop global
// w-loads didn't help, so w BW wasn't R2's limiter; pipelining was.
// R5: w REGISTER-resident (SSEG=8 -> 4o x 8s quads = 128 VGPR, loaded once),
// each wave walks 16 b rows; inner loop = pure x stream, ping-pong 4-load
// half-steps. ~200 VGPR, 2 waves/SIMD, grid (10,4,50) = 2000 waves all
// resident. ws = 50 slices (128 MB, L3-resident); reduce folds 50 + bias.

constexpr int IN_F   = 1000000;
constexpr int S_DIM  = 400;
constexpr int C_DIM  = 2500;
constexpr int O_SETS = 4;
constexpr int B_SZ   = 64;
constexpr int OC     = O_SETS * C_DIM;    // 10000
constexpr int OUT_N  = B_SZ * OC;         // 640000

constexpr int NQ     = C_DIM / 4;         // 625 float4 quads along c
constexpr int QW     = (NQ + 63) / 64;    // 10 c-blocks of 64 quads
constexpr int NSPLIT = 50;                // s segments
constexpr int SSEG   = S_DIM / NSPLIT;    // 8 s-steps per segment (reg-resident w)
constexpr int BPW    = 16;                // b rows walked per wave
constexpr int BGRP   = B_SZ / BPW;        // 4 b-groups

constexpr size_t WS_NEED = (size_t)NSPLIT * OUT_N * sizeof(float);  // 128 MB

__device__ __forceinline__ void fma4(float4& a, const float4& p, const float4& q) {
    a.x = fmaf(p.x, q.x, a.x);
    a.y = fmaf(p.y, q.y, a.y);
    a.z = fmaf(p.z, q.z, a.z);
    a.w = fmaf(p.w, q.w, a.w);
}

// ---------------- Main path ----------------

// grid (QW, BGRP, NSPLIT), block = 1 wave (64 thr).
__global__ __launch_bounds__(64, 2) void sl_part(const float* __restrict__ x,
                                                 const float* __restrict__ w,
                                                 float* __restrict__ ws) {
    const int lane = threadIdx.x;
    const int q    = blockIdx.x * 64 + lane;
    const bool act = (q < NQ);
    const int qc   = act ? q : NQ - 1;     // clamped: keeps junk loads in-bounds
    const int b0   = blockIdx.y * BPW;
    const int z    = blockIdx.z;
    const int s0   = z * SSEG;

    // w -> registers, once. wreg[o][s], 32 quads = 128 VGPR.
    float4 wreg[O_SETS][SSEG];
#pragma unroll
    for (int o = 0; o < O_SETS; ++o)
#pragma unroll
        for (int s = 0; s < SSEG; ++s)
            wreg[o][s] = *(const float4*)(w + (size_t)o * (S_DIM * C_DIM)
                                            + (size_t)(s0 + s) * C_DIM
                                            + (size_t)qc * 4);

    const float* xbase = x + (size_t)s0 * C_DIM + (size_t)qc * 4;

    float4 xb[2][4];      // ping-pong half-steps (4 s each)
    float4 acc[O_SETS];
#pragma unroll
    for (int o = 0; o < O_SETS; ++o) acc[o] = make_float4(0.f, 0.f, 0.f, 0.f);

    // prologue: first half of first b
    {
        const float* row = xbase + (size_t)b0 * IN_F;
#pragma unroll
        for (int j = 0; j < 4; ++j)
            xb[0][j] = *(const float4*)(row + (size_t)j * C_DIM);
    }

    for (int b = 0; b < BPW; ++b) {
        const float* row = xbase + (size_t)(b0 + b) * IN_F;

        // issue second half of b
#pragma unroll
        for (int j = 0; j < 4; ++j)
            xb[1][j] = *(const float4*)(row + (size_t)(4 + j) * C_DIM);

        // compute first half (s = 0..3)
#pragma unroll
        for (int j = 0; j < 4; ++j)
#pragma unroll
            for (int o = 0; o < O_SETS; ++o)
                fma4(acc[o], xb[0][j], wreg[o][j]);

        // issue first half of b+1
        if (b + 1 < BPW) {
            const float* nrow = xbase + (size_t)(b0 + b + 1) * IN_F;
#pragma unroll
            for (int j = 0; j < 4; ++j)
                xb[0][j] = *(const float4*)(nrow + (size_t)j * C_DIM);
        }

        // compute second half (s = 4..7)
#pragma unroll
        for (int j = 0; j < 4; ++j)
#pragma unroll
            for (int o = 0; o < O_SETS; ++o)
                fma4(acc[o], xb[1][j], wreg[o][4 + j]);

        // store partials for this b, reset acc
        if (act) {
            float* orow = ws + (size_t)z * OUT_N + (size_t)(b0 + b) * OC;
#pragma unroll
            for (int o = 0; o < O_SETS; ++o)
                *(float4*)(orow + o * C_DIM + q * 4) = acc[o];
        }
#pragma unroll
        for (int o = 0; o < O_SETS; ++o) acc[o] = make_float4(0.f, 0.f, 0.f, 0.f);
    }
}

// out[idx] = bias[idx % OC] + sum_z ws[z][idx]
__global__ __launch_bounds__(256) void sl_reduce(const float* __restrict__ ws,
                                                 const float* __restrict__ bias,
                                                 float* __restrict__ out) {
    const int t = blockIdx.x * 256 + threadIdx.x;
    if (t >= OUT_N / 4) return;
    const int idx = t * 4;
    const int oc  = idx % OC;   // OC % 4 == 0 -> a float4 never crosses rows

    float4 s0 = *(const float4*)(bias + oc);
    float4 s1 = make_float4(0.f, 0.f, 0.f, 0.f);
#pragma unroll 10
    for (int z = 0; z < NSPLIT; z += 2) {
        float4 v0 = *(const float4*)(ws + (size_t)z * OUT_N + idx);
        float4 v1 = *(const float4*)(ws + (size_t)(z + 1) * OUT_N + idx);
        s0.x += v0.x; s0.y += v0.y; s0.z += v0.z; s0.w += v0.w;
        s1.x += v1.x; s1.y += v1.y; s1.z += v1.z; s1.w += v1.w;
    }
    s0.x += s1.x; s0.y += s1.y; s0.z += s1.z; s0.w += s1.w;
    *(float4*)(out + idx) = s0;
}

// ---------------- Fallback (ws too small): atomics ----------------

__global__ __launch_bounds__(256) void sl_init(const float* __restrict__ bias,
                                               float* __restrict__ out) {
    int j = blockIdx.x * 256 + threadIdx.x;
    if (j < OC) out[(size_t)blockIdx.y * OC + j] = bias[j];
}

__global__ __launch_bounds__(64) void sl_atomic(const float* __restrict__ x,
                                                const float* __restrict__ w,
                                                float* __restrict__ out) {
    const int lane = threadIdx.x;
    const int q    = blockIdx.x * 64 + lane;
    if (q >= NQ) return;
    const int b  = blockIdx.y;
    const int s0 = blockIdx.z * SSEG;

    const float4* xp = (const float4*)(x + (size_t)b * IN_F + (size_t)s0 * C_DIM) + q;
    const float4* wp[O_SETS];
#pragma unroll
    for (int o = 0; o < O_SETS; ++o)
        wp[o] = (const float4*)(w + (size_t)o * (S_DIM * C_DIM) + (size_t)s0 * C_DIM) + q;

    float4 acc[O_SETS];
#pragma unroll
    for (int o = 0; o < O_SETS; ++o) acc[o] = make_float4(0.f, 0.f, 0.f, 0.f);

    for (int s = 0; s < SSEG; ++s) {
        float4 xv = *xp; xp += C_DIM / 4;
        float4 wv4[O_SETS];
#pragma unroll
        for (int o = 0; o < O_SETS; ++o) { wv4[o] = *wp[o]; wp[o] += C_DIM / 4; }
#pragma unroll
        for (int o = 0; o < O_SETS; ++o) fma4(acc[o], xv, wv4[o]);
    }

    float* orow = out + (size_t)b * OC;
#pragma unroll
    for (int o = 0; o < O_SETS; ++o) {
        float* dst = orow + o * C_DIM + q * 4;
        atomicAdd(dst + 0, acc[o].x);
        atomicAdd(dst + 1, acc[o].y);
        atomicAdd(dst + 2, acc[o].z);
        atomicAdd(dst + 3, acc[o].w);
    }
}

extern "C" void kernel_launch(void* const* d_in, const int* in_sizes, int n_in,
                              void* d_out, int out_size, void* d_ws, size_t ws_size,
                              hipStream_t stream) {
    const float* x    = (const float*)d_in[0];
    const float* wgt  = (const float*)d_in[1];
    const float* bias = (const float*)d_in[2];
    float* out = (float*)d_out;

    if (ws_size >= WS_NEED) {
        float* ws = (float*)d_ws;
        dim3 g(QW, BGRP, NSPLIT);
        sl_part<<<g, 64, 0, stream>>>(x, wgt, ws);
        sl_reduce<<<(OUT_N / 4 + 255) / 256, 256, 0, stream>>>(ws, bias, out);
    } else {
        dim3 gInit((OC + 255) / 256, B_SZ);
        sl_init<<<gInit, 256, 0, stream>>>(bias, out);
        dim3 g(QW, B_SZ, NSPLIT);
        sl_atomic<<<g, 64, 0, stream>>>(x, wgt, out);
    }
}

// Round 6
// 376.974 us; speedup vs baseline: 1.1596x; 1.0608x over previous
//
#include <hip/hip_runtime.h>

// SplitLinear: out[b, o*C + c] = sum_s x[b, s*C + c] * w[o, s, c] + bias[o*C + c]
// x: [64, 1e6] fp32, w: [4, 400, 2500] fp32, bias: [10000], out: [64, 10000]
//
// R2/R3/R5 post-mortem: three different structures (w streamed, w in LDS,
// w register-resident) ALL plateau at ~2.5-3.5 TB/s while harness fill/d2d
// run 6.6 TB/s. Common factor: 1 KB wave-bursts at 10 KB stride (c-quad x 64
// lanes, then +C_DIM). Theory: DRAM burst/row-buffer efficiency ~50% for
// short strided bursts. R6: 256-thr blocks cover 256 CONTIGUOUS c-quads ->
// 4 KB bursts for x and w per step; otherwise R2's best shape (BT=4 b-rows,
// acc in regs across SSEG=25 s-steps, stores only in epilogue). NSPLIT=16,
// ws = 41 MB. grid (3,16,16) = 768 blocks.

constexpr int IN_F   = 1000000;
constexpr int S_DIM  = 400;
constexpr int C_DIM  = 2500;
constexpr int O_SETS = 4;
constexpr int B_SZ   = 64;
constexpr int OC     = O_SETS * C_DIM;    // 10000
constexpr int OUT_N  = B_SZ * OC;         // 640000

constexpr int NQ     = C_DIM / 4;         // 625 float4 quads along c
constexpr int CB     = 3;                 // c-blocks of 256 quads (4 KB bursts)
constexpr int NSPLIT = 16;                // s segments
constexpr int SSEG   = S_DIM / NSPLIT;    // 25 s-steps per segment
constexpr int BT     = 4;                 // b rows per thread
constexpr int BGRP   = B_SZ / BT;         // 16
constexpr int STEPQ  = C_DIM / 4;         // float4 stride per s-step

constexpr size_t WS_NEED = (size_t)NSPLIT * OUT_N * sizeof(float);  // 41 MB

__device__ __forceinline__ void fma4(float4& a, const float4& p, const float4& q) {
    a.x = fmaf(p.x, q.x, a.x);
    a.y = fmaf(p.y, q.y, a.y);
    a.z = fmaf(p.z, q.z, a.z);
    a.w = fmaf(p.w, q.w, a.w);
}

// ---------------- Main path ----------------

// grid (CB, BGRP, NSPLIT), block = 256 thr. Thread -> c-quad q0+tid (block
// spans 4 KB contiguous); BT=4 b-rows, 4 o-sets, acc over SSEG s-steps.
__global__ __launch_bounds__(256, 2) void sl_part(const float* __restrict__ x,
                                                  const float* __restrict__ w,
                                                  float* __restrict__ ws) {
    const int tid = threadIdx.x;
    const int q   = blockIdx.x * 256 + tid;
    const bool act = (q < NQ);
    const int qc  = act ? q : NQ - 1;      // clamp: junk loads stay in-bounds
    const int b0  = blockIdx.y * BT;
    const int z   = blockIdx.z;
    const int s0  = z * SSEG;

    const float4* xp[BT];
#pragma unroll
    for (int i = 0; i < BT; ++i)
        xp[i] = (const float4*)(x + (size_t)(b0 + i) * IN_F + (size_t)s0 * C_DIM) + qc;

    const float4* wp[O_SETS];
#pragma unroll
    for (int o = 0; o < O_SETS; ++o)
        wp[o] = (const float4*)(w + (size_t)o * (S_DIM * C_DIM) + (size_t)s0 * C_DIM) + qc;

    float4 acc[BT][O_SETS];
#pragma unroll
    for (int i = 0; i < BT; ++i)
#pragma unroll
        for (int o = 0; o < O_SETS; ++o)
            acc[i][o] = make_float4(0.f, 0.f, 0.f, 0.f);

    // Ping-pong register prefetch: 8 loads in flight while 64 fma4 run.
    float4 xb[2][BT], wb[2][O_SETS];
#pragma unroll
    for (int i = 0; i < BT; ++i) { xb[0][i] = *xp[i]; xp[i] += STEPQ; }
#pragma unroll
    for (int o = 0; o < O_SETS; ++o) { wb[0][o] = *wp[o]; wp[o] += STEPQ; }

#pragma unroll
    for (int s = 0; s < SSEG; ++s) {
        const int cur = s & 1, nxt = cur ^ 1;
        if (s + 1 < SSEG) {   // compile-time after full unroll
#pragma unroll
            for (int i = 0; i < BT; ++i) { xb[nxt][i] = *xp[i]; xp[i] += STEPQ; }
#pragma unroll
            for (int o = 0; o < O_SETS; ++o) { wb[nxt][o] = *wp[o]; wp[o] += STEPQ; }
        }
#pragma unroll
        for (int i = 0; i < BT; ++i)
#pragma unroll
            for (int o = 0; o < O_SETS; ++o)
                fma4(acc[i][o], xb[cur][i], wb[cur][o]);
    }

    if (act) {
        float* base = ws + (size_t)z * OUT_N;
#pragma unroll
        for (int i = 0; i < BT; ++i) {
            float* orow = base + (size_t)(b0 + i) * OC;
#pragma unroll
            for (int o = 0; o < O_SETS; ++o)
                *(float4*)(orow + o * C_DIM + q * 4) = acc[i][o];
        }
    }
}

// out[idx] = bias[idx % OC] + sum_z ws[z][idx]
__global__ __launch_bounds__(256) void sl_reduce(const float* __restrict__ ws,
                                                 const float* __restrict__ bias,
                                                 float* __restrict__ out) {
    const int t = blockIdx.x * 256 + threadIdx.x;
    if (t >= OUT_N / 4) return;
    const int idx = t * 4;
    const int oc  = idx % OC;   // OC % 4 == 0 -> a float4 never crosses rows

    float4 s0 = *(const float4*)(bias + oc);
    float4 s1 = make_float4(0.f, 0.f, 0.f, 0.f);
#pragma unroll
    for (int z = 0; z < NSPLIT; z += 2) {
        float4 v0 = *(const float4*)(ws + (size_t)z * OUT_N + idx);
        float4 v1 = *(const float4*)(ws + (size_t)(z + 1) * OUT_N + idx);
        s0.x += v0.x; s0.y += v0.y; s0.z += v0.z; s0.w += v0.w;
        s1.x += v1.x; s1.y += v1.y; s1.z += v1.z; s1.w += v1.w;
    }
    s0.x += s1.x; s0.y += s1.y; s0.z += s1.z; s0.w += s1.w;
    *(float4*)(out + idx) = s0;
}

// ---------------- Fallback (ws too small): atomics ----------------

__global__ __launch_bounds__(256) void sl_init(const float* __restrict__ bias,
                                               float* __restrict__ out) {
    int j = blockIdx.x * 256 + threadIdx.x;
    if (j < OC) out[(size_t)blockIdx.y * OC + j] = bias[j];
}

__global__ __launch_bounds__(64) void sl_atomic(const float* __restrict__ x,
                                                const float* __restrict__ w,
                                                float* __restrict__ out) {
    const int lane = threadIdx.x;
    const int q    = blockIdx.x * 64 + lane;
    if (q >= NQ) return;
    const int b  = blockIdx.y;
    const int s0 = blockIdx.z * SSEG;

    const float4* xp = (const float4*)(x + (size_t)b * IN_F + (size_t)s0 * C_DIM) + q;
    const float4* wp[O_SETS];
#pragma unroll
    for (int o = 0; o < O_SETS; ++o)
        wp[o] = (const float4*)(w + (size_t)o * (S_DIM * C_DIM) + (size_t)s0 * C_DIM) + q;

    float4 acc[O_SETS];
#pragma unroll
    for (int o = 0; o < O_SETS; ++o) acc[o] = make_float4(0.f, 0.f, 0.f, 0.f);

    for (int s = 0; s < SSEG; ++s) {
        float4 xv = *xp; xp += STEPQ;
        float4 wv4[O_SETS];
#pragma unroll
        for (int o = 0; o < O_SETS; ++o) { wv4[o] = *wp[o]; wp[o] += STEPQ; }
#pragma unroll
        for (int o = 0; o < O_SETS; ++o) fma4(acc[o], xv, wv4[o]);
    }

    float* orow = out + (size_t)b * OC;
#pragma unroll
    for (int o = 0; o < O_SETS; ++o) {
        float* dst = orow + o * C_DIM + q * 4;
        atomicAdd(dst + 0, acc[o].x);
        atomicAdd(dst + 1, acc[o].y);
        atomicAdd(dst + 2, acc[o].z);
        atomicAdd(dst + 3, acc[o].w);
    }
}

extern "C" void kernel_launch(void* const* d_in, const int* in_sizes, int n_in,
                              void* d_out, int out_size, void* d_ws, size_t ws_size,
                              hipStream_t stream) {
    const float* x    = (const float*)d_in[0];
    const float* wgt  = (const float*)d_in[1];
    const float* bias = (const float*)d_in[2];
    float* out = (float*)d_out;

    if (ws_size >= WS_NEED) {
        float* ws = (float*)d_ws;
        dim3 g(CB, BGRP, NSPLIT);
        sl_part<<<g, 256, 0, stream>>>(x, wgt, ws);
        sl_reduce<<<(OUT_N / 4 + 255) / 256, 256, 0, stream>>>(ws, bias, out);
    } else {
        dim3 gInit((OC + 255) / 256, B_SZ);
        sl_init<<<gInit, 256, 0, stream>>>(bias, out);
        dim3 g((NQ + 63) / 64, B_SZ, NSPLIT);
        sl_atomic<<<g, 64, 0, stream>>>(x, wgt, out);
    }
}